// Round 4
// baseline (902.117 us; speedup 1.0000x reference)
//
#include <hip/hip_runtime.h>
#include <stdint.h>

// HashEncoder (Instant-NGP / HashNeRF): 1M points, 16 levels, 2 feats, 2^19 table.
// R4: single fused kernel. Thread = point, unrolled 16-level loop, LDS-staged
// transpose (two 8-level passes) for full-line coalesced out writes.
// Eliminates the 128MB ws write + 128MB ws read + second dispatch of R1-R3.
// Tradeoff being measured: gathers lose per-XCD-L2 level residency -> L3.

static constexpr int NP = 1048576;
static constexpr int NL = 16;
static constexpr int TPB = 256;
static constexpr uint32_t HMASK = (1u << 19) - 1u;

// res_i = floor(16 * b^i), b = f32(exp((ln512-ln16)/15)) = 1.2599210739135742 (> 2^(1/3))
// -> power-of-two levels floor on the UP side: 32/64/128/256/512. Verified R1-R3: absmax 2.4e-7.
__constant__ float c_res[NL] = {16.f, 20.f, 25.f, 32.f, 40.f, 50.f, 64.f, 80.f,
                                101.f, 128.f, 161.f, 203.f, 256.f, 322.f, 406.f, 512.f};

__device__ __forceinline__ float2 enc_one(
    float x0, float x1, float x2,
    float b0, float b1, float b2,
    float B0, float B1, float B2,
    const float2* __restrict__ tab, float res, float gate)
{
    // index path must be bit-exact vs numpy f32: sub/div/floor only (no contraction possible)
    float g0 = (B0 - b0) / res;
    float g1 = (B1 - b1) / res;
    float g2 = (B2 - b2) / res;
    float xc0 = fminf(fmaxf(x0, b0), B0);
    float xc1 = fminf(fmaxf(x1, b1), B1);
    float xc2 = fminf(fmaxf(x2, b2), B2);
    float f0 = floorf((xc0 - b0) / g0);
    float f1 = floorf((xc1 - b1) / g1);
    float f2 = floorf((xc2 - b2) / g2);
    // interpolation weights use RAW x (per reference); rounding here is ~1e-11 on output
    float v0 = f0 * g0 + b0;
    float v1 = f1 * g1 + b1;
    float v2 = f2 * g2 + b2;
    float w0 = (x0 - v0) / ((v0 + g0) - v0);
    float w1 = (x1 - v1) / ((v1 + g1) - v1);
    float w2 = (x2 - v2) / ((v2 + g2) - v2);

    uint32_t u0 = (uint32_t)(int)f0;
    uint32_t u1 = (uint32_t)(int)f1;
    uint32_t u2 = (uint32_t)(int)f2;
    uint32_t ya = u1 * 2654435761u, yb = (u1 + 1u) * 2654435761u;
    uint32_t za = u2 * 805459861u,  zb = (u2 + 1u) * 805459861u;
    uint32_t xa = u0, xb = u0 + 1u;

    // corner index = i*4 + j*2 + k (i on x, j on y, k on z)
    float2 e000 = tab[(xa ^ ya ^ za) & HMASK];
    float2 e001 = tab[(xa ^ ya ^ zb) & HMASK];
    float2 e010 = tab[(xa ^ yb ^ za) & HMASK];
    float2 e011 = tab[(xa ^ yb ^ zb) & HMASK];
    float2 e100 = tab[(xb ^ ya ^ za) & HMASK];
    float2 e101 = tab[(xb ^ ya ^ zb) & HMASK];
    float2 e110 = tab[(xb ^ yb ^ za) & HMASK];
    float2 e111 = tab[(xb ^ yb ^ zb) & HMASK];

    float s0 = 1.f - w0, s1 = 1.f - w1, s2 = 1.f - w2;
    // blend x
    float cx00x = e000.x * s0 + e100.x * w0, cx00y = e000.y * s0 + e100.y * w0;
    float cx01x = e001.x * s0 + e101.x * w0, cx01y = e001.y * s0 + e101.y * w0;
    float cx10x = e010.x * s0 + e110.x * w0, cx10y = e010.y * s0 + e110.y * w0;
    float cx11x = e011.x * s0 + e111.x * w0, cx11y = e011.y * s0 + e111.y * w0;
    // blend y
    float c0x = cx00x * s1 + cx10x * w1, c0y = cx00y * s1 + cx10y * w1;
    float c1x = cx01x * s1 + cx11x * w1, c1y = cx01y * s1 + cx11y * w1;
    // blend z
    float ox = c0x * s2 + c1x * w2;
    float oy = c0y * s2 + c1y * w2;
    return make_float2(ox * gate, oy * gate);
}

// Fused: block = 256 points. For each half h (levels 8h..8h+7):
//   compute 8 float2 results -> LDS s[256][9] (pad row: trivial conflicts) ->
//   4 float4 stores/thread; each 64B out line fully written by 4 lanes of one wave.
// LDS 18,432 B -> up to 8 blocks/CU by LDS; VGPR expected ~80-100.
__global__ __launch_bounds__(TPB) void k_all(
    const float* __restrict__ x, const float* __restrict__ emb,
    const float* __restrict__ lw, const float* __restrict__ bmin,
    const float* __restrict__ bmax, float4* __restrict__ out)
{
    __shared__ float2 s[256][9];
    int t = threadIdx.x;
    size_t p0 = (size_t)blockIdx.x * TPB;
    size_t p = p0 + (size_t)t;

    float x0 = x[3 * p + 0], x1 = x[3 * p + 1], x2 = x[3 * p + 2];
    float b0 = bmin[0], b1 = bmin[1], b2 = bmin[2];
    float B0 = bmax[0], B1 = bmax[1], B2 = bmax[2];

#pragma unroll
    for (int h = 0; h < 2; ++h) {
        float2 o[8];
#pragma unroll
        for (int m = 0; m < 8; ++m) {
            int l = h * 8 + m;
            float gate = 1.0f / (1.0f + expf(-lw[l]));
            const float2* tab = (const float2*)(emb + ((size_t)l << 20));
            o[m] = enc_one(x0, x1, x2, b0, b1, b2, B0, B1, B2, tab, c_res[l], gate);
        }
        if (h) __syncthreads();   // previous half's LDS reads must drain
#pragma unroll
        for (int m = 0; m < 8; ++m) s[t][m] = o[m];
        __syncthreads();
#pragma unroll
        for (int k = 0; k < 4; ++k) {
            int mm = k * 256 + t;       // 0..1023: float4 slot within half-tile
            int q = mm >> 2;            // local point
            int j = mm & 3;             // float4 within half-row (levels 2j,2j+1 of half)
            float2 a = s[q][2 * j];
            float2 b = s[q][2 * j + 1];
            out[(p0 + (size_t)q) * 8 + h * 4 + j] = make_float4(a.x, a.y, b.x, b.y);
        }
    }
}

extern "C" void kernel_launch(void* const* d_in, const int* in_sizes, int n_in,
                              void* d_out, int out_size, void* d_ws, size_t ws_size,
                              hipStream_t stream) {
    const float* x    = (const float*)d_in[0];
    const float* emb  = (const float*)d_in[1];
    const float* lw   = (const float*)d_in[2];
    const float* bmin = (const float*)d_in[3];
    const float* bmax = (const float*)d_in[4];
    float4* out = (float4*)d_out;
    (void)d_ws; (void)ws_size;

    k_all<<<NP / TPB, TPB, 0, stream>>>(x, emb, lw, bmin, bmax, out);
}